// Round 17
// baseline (365.101 us; speedup 1.0000x reference)
//
#include <hip/hip_runtime.h>
#include <math.h>

typedef unsigned short ushort_t;
typedef __attribute__((ext_vector_type(8))) short short8;
typedef __attribute__((ext_vector_type(4))) float f32x4;
typedef __attribute__((ext_vector_type(4))) unsigned short us4;

__device__ __forceinline__ unsigned short f2bf(float f) {
    unsigned u = __float_as_uint(f);
    unsigned r = (u + 0x7fffu + ((u >> 16) & 1u)) >> 16;   // RNE
    return (unsigned short)r;
}
__device__ __forceinline__ float bf2f(unsigned short b) {
    return __uint_as_float(((unsigned)b) << 16);
}

__device__ __forceinline__ void gld_lds16(const ushort_t* g, ushort_t* l) {
    __builtin_amdgcn_global_load_lds(
        (const __attribute__((address_space(1))) unsigned int*)g,
        (__attribute__((address_space(3))) unsigned int*)l,
        16, 0, 0);
}

#define AGG_BLOCKS 2048

// ---------------- fused prep: x->bf16, W1->W1t, W2->W2t ----------------

__global__ __launch_bounds__(256) void prep_kernel(const float* __restrict__ x,
                                                   ushort_t* __restrict__ xb, int n4, int XB,
                                                   const float* __restrict__ W1,
                                                   ushort_t* __restrict__ w1t,
                                                   const float* __restrict__ W2,
                                                   ushort_t* __restrict__ w2t) {
    int b = blockIdx.x;
    if (b < XB) {
        int i = b * 256 + threadIdx.x;
        if (i < n4) {
            float4 v = *(const float4*)(x + (size_t)i * 4);
            ushort4 q;
            q.x = f2bf(v.x); q.y = f2bf(v.y); q.z = f2bf(v.z); q.w = f2bf(v.w);
            *(ushort4*)(xb + (size_t)i * 4) = q;
        }
    } else if (b < XB + 128) {
        int idx = (b - XB) * 256 + threadIdx.x;   // over 128*256
        int k = idx >> 8, n = idx & 255;
        w1t[(size_t)n * 128 + k] = f2bf(W1[idx]);
    } else {
        int idx = (b - XB - 128) * 256 + threadIdx.x; // over 256*256
        int k = idx >> 8, n = idx & 255;
        w2t[(size_t)n * 256 + k] = f2bf(W2[idx]);
    }
}

// ---------------- CSR build: hist assigns within-segment rank ----------------

__global__ __launch_bounds__(256) void hist_kernel(const int* __restrict__ dst, int E,
                                                   int* __restrict__ deg,
                                                   int* __restrict__ rank) {
    int e = blockIdx.x * 256 + threadIdx.x;
    if (e < E) rank[e] = atomicAdd(&deg[dst[e]], 1);
}

__global__ __launch_bounds__(256) void scan_block(const int* __restrict__ in, int n,
                                                  int* __restrict__ out, int* __restrict__ bsums) {
    __shared__ int s[256];
    int t = threadIdx.x;
    int i = blockIdx.x * 256 + t;
    int v = (i < n) ? in[i] : 0;
    s[t] = v;
    __syncthreads();
#pragma unroll
    for (int o = 1; o < 256; o <<= 1) {
        int y = (t >= o) ? s[t - o] : 0;
        __syncthreads();
        s[t] += y;
        __syncthreads();
    }
    if (i < n) out[i] = s[t] - v;
    if (t == 255) bsums[blockIdx.x] = s[255];
}

__global__ __launch_bounds__(256) void scan_sums(int* __restrict__ bsums, int nb) {
    __shared__ int s[256];
    int t = threadIdx.x;
    int v = (t < nb) ? bsums[t] : 0;
    s[t] = v;
    __syncthreads();
#pragma unroll
    for (int o = 1; o < 256; o <<= 1) {
        int y = (t >= o) ? s[t - o] : 0;
        __syncthreads();
        s[t] += y;
        __syncthreads();
    }
    if (t < nb) bsums[t] = s[t] - v;
}

__global__ __launch_bounds__(256) void scan_add(int* __restrict__ off,
                                                const int* __restrict__ bsums, int N, int E) {
    int i = blockIdx.x * 256 + threadIdx.x;
    if (i < N) off[i] += bsums[blockIdx.x];
    if (i == 0) off[N] = E;
}

// ---------------- CSR placement: (src,dst) packed, ONE 8B random store/edge ----------------

__global__ __launch_bounds__(256) void scatter_inv_kernel(const int* __restrict__ ei, int E,
                                                          const int* __restrict__ off,
                                                          const int* __restrict__ rank,
                                                          int2* __restrict__ epair) {
    int e = blockIdx.x * 256 + threadIdx.x;
    if (e < E) {
        int s = ei[e], d = ei[E + e];
        int pos = off[d] + rank[e];
        epair[pos] = make_int2(s, d);
    }
}

// ---------------- bf16 MFMA GEMM + fused alpha epilogue ----------------

__device__ __forceinline__ int swz4(int r) { return (r ^ (r >> 2)) & 3; }

__global__ __launch_bounds__(256) void gemm_mfma(const ushort_t* __restrict__ A,
                                                 const ushort_t* __restrict__ Bt,
                                                 ushort_t* __restrict__ C, int M, int K,
                                                 const float* __restrict__ a_src,
                                                 const float* __restrict__ a_dst,
                                                 float* __restrict__ aS,
                                                 float* __restrict__ aD) {
    __shared__ ushort_t smem[2 * 128 * 32];     // K-loop: As | Bs ; epilogue: [64][128] stage
    ushort_t* As = smem;
    ushort_t* Bs = smem + 128 * 32;
    const int tid = threadIdx.x;
    const int lane = tid & 63;
    const int wave = tid >> 6;
    const int bm = blockIdx.x * 128;
    const int bn = blockIdx.y * 128;
    const int head_base = blockIdx.y * 4;
    const int wr = (wave >> 1) * 64;
    const int wc = (wave & 1) * 64;

    const int G0 = wave * 2, G1 = wave * 2 + 1;
    const int rl = lane >> 2;
    const int sl = lane & 3;
    const int RA0 = G0 * 16 + rl, RA1 = G1 * 16 + rl;
    const int sA0 = sl ^ swz4(RA0), sA1 = sl ^ swz4(RA1);
    const int gA0 = min(bm + RA0, M - 1);
    const int gA1 = min(bm + RA1, M - 1);
    const ushort_t* srcA0 = A + (size_t)gA0 * K + sA0 * 8;
    const ushort_t* srcA1 = A + (size_t)gA1 * K + sA1 * 8;
    const ushort_t* srcB0 = Bt + (size_t)(bn + RA0) * K + sA0 * 8;
    const ushort_t* srcB1 = Bt + (size_t)(bn + RA1) * K + sA1 * 8;
    ushort_t* dA0 = &As[G0 * 512];
    ushort_t* dA1 = &As[G1 * 512];
    ushort_t* dB0 = &Bs[G0 * 512];
    ushort_t* dB1 = &Bs[G1 * 512];

    int offA[4], offB[4];
    const int c = lane >> 4;
    const int fr = lane & 15;
#pragma unroll
    for (int mi = 0; mi < 4; mi++) {
        int r = wr + mi * 16 + fr;
        offA[mi] = r * 32 + (c ^ swz4(r)) * 8;
    }
#pragma unroll
    for (int ni = 0; ni < 4; ni++) {
        int r = wc + ni * 16 + fr;
        offB[ni] = r * 32 + (c ^ swz4(r)) * 8;
    }

    f32x4 acc[4][4];
#pragma unroll
    for (int i = 0; i < 4; i++)
#pragma unroll
        for (int j = 0; j < 4; j++)
            acc[i][j] = (f32x4){0.f, 0.f, 0.f, 0.f};

    const int nk = K >> 5;
    gld_lds16(srcA0, dA0);
    gld_lds16(srcA1, dA1);
    gld_lds16(srcB0, dB0);
    gld_lds16(srcB1, dB1);

    for (int kk = 0; kk < nk; kk++) {
        __syncthreads();
        short8 af[4], bf[4];
#pragma unroll
        for (int mi = 0; mi < 4; mi++) af[mi] = *(const short8*)&As[offA[mi]];
#pragma unroll
        for (int ni = 0; ni < 4; ni++) bf[ni] = *(const short8*)&Bs[offB[ni]];
#pragma unroll
        for (int mi = 0; mi < 4; mi++)
#pragma unroll
            for (int ni = 0; ni < 4; ni++)
                acc[mi][ni] = __builtin_amdgcn_mfma_f32_16x16x32_bf16(af[mi], bf[ni],
                                                                      acc[mi][ni], 0, 0, 0);
        __syncthreads();
        if (kk + 1 < nk) {
            int k0 = (kk + 1) * 32;
            gld_lds16(srcA0 + k0, dA0);
            gld_lds16(srcA1 + k0, dA1);
            gld_lds16(srcB0 + k0, dB0);
            gld_lds16(srcB1 + k0, dB1);
        }
    }

    // epilogue: stage 64 rows in LDS; b128 global stores; fused alpha dots.
    const int rq = (lane >> 4) * 4;
#pragma unroll
    for (int half = 0; half < 2; half++) {
        __syncthreads();
        if ((wave >> 1) == half) {
#pragma unroll
            for (int mi = 0; mi < 4; mi++)
#pragma unroll
                for (int j = 0; j < 4; j++) {
                    int rowl = mi * 16 + rq + j;
#pragma unroll
                    for (int ni = 0; ni < 4; ni++)
                        smem[rowl * 128 + wc + ni * 16 + fr] = f2bf(acc[mi][ni][j]);
                }
        }
        __syncthreads();
#pragma unroll
        for (int q2 = 0; q2 < 4; q2++) {
            int cidx = q2 * 256 + tid;       // 16B-chunk index 0..1023 in [64][128]
            int r = cidx >> 4;               // row 0..63
            int ck = cidx & 15;              // chunk in row (8 cols each)
            int grow = bm + half * 64 + r;
            uint4 v = *(const uint4*)&smem[cidx * 8];
            if (grow < M)
                *(uint4*)(C + (size_t)grow * 256 + bn + ck * 8) = v;
            int hd = ck >> 2, qq = ck & 3;
            const float* apS = a_src + (head_base + hd) * 32 + qq * 8;
            const float* apD = a_dst + (head_base + hd) * 32 + qq * 8;
            float4 s0v = *(const float4*)apS, s1v = *(const float4*)(apS + 4);
            float4 d0v = *(const float4*)apD, d1v = *(const float4*)(apD + 4);
            unsigned uu[4] = {v.x, v.y, v.z, v.w};
            float as_[8] = {s0v.x, s0v.y, s0v.z, s0v.w, s1v.x, s1v.y, s1v.z, s1v.w};
            float ad_[8] = {d0v.x, d0v.y, d0v.z, d0v.w, d1v.x, d1v.y, d1v.z, d1v.w};
            float sp = 0.f, dp = 0.f;
#pragma unroll
            for (int pp = 0; pp < 4; pp++) {
                float h0 = bf2f((unsigned short)(uu[pp] & 0xffffu));
                float h1 = bf2f((unsigned short)(uu[pp] >> 16));
                sp = fmaf(h0, as_[2 * pp], sp);
                sp = fmaf(h1, as_[2 * pp + 1], sp);
                dp = fmaf(h0, ad_[2 * pp], dp);
                dp = fmaf(h1, ad_[2 * pp + 1], dp);
            }
            sp += __shfl_xor(sp, 1);
            sp += __shfl_xor(sp, 2);
            dp += __shfl_xor(dp, 1);
            dp += __shfl_xor(dp, 2);
            if (qq == 0 && grow < M) {
                aS[(size_t)grow * 8 + head_base + hd] = sp;
                aD[(size_t)grow * 8 + head_base + hd] = dp;
            }
        }
    }
}

// ---------------- position-major p = exp(leaky(aS+aD)): coalesced epair read ----------------

__global__ __launch_bounds__(256) void pexp_stream_kernel(const int2* __restrict__ epair,
                                                          const float* __restrict__ aS,
                                                          const float* __restrict__ aD,
                                                          ushort_t* __restrict__ pB, int E) {
    int j = blockIdx.x * 256 + threadIdx.x;
    if (j >= E) return;
    int2 sd = epair[j];
    const float4* sp = (const float4*)(aS + (size_t)sd.x * 8);
    const float4* dp = (const float4*)(aD + (size_t)sd.y * 8);
    float4 sv0 = sp[0], sv1 = sp[1], dv0 = dp[0], dv1 = dp[1];
    float ev[8] = {sv0.x + dv0.x, sv0.y + dv0.y, sv0.z + dv0.z, sv0.w + dv0.w,
                   sv1.x + dv1.x, sv1.y + dv1.y, sv1.z + dv1.z, sv1.w + dv1.w};
    ushort_t q[8];
#pragma unroll
    for (int h = 0; h < 8; h++) {
        float x = ev[h];
        x = (x > 0.f) ? x : 0.2f * x;
        q[h] = f2bf(__expf(x));
    }
    *(uint4*)(pB + (size_t)j * 8) = *(uint4*)q;
}

// ---------------- aggregate (layer 1): 6-deep explicit scalars -> out ----------------
// Persistent 2048 blocks x 4 waves; nontemporal h loads (us4 = clang ext_vector).

__global__ __launch_bounds__(256) void aggregate_kernel(const ushort_t* __restrict__ hb,
                                                        const ushort_t* __restrict__ pB,
                                                        const int* __restrict__ off,
                                                        const int2* __restrict__ epair,
                                                        const float* __restrict__ bias,
                                                        ushort_t* __restrict__ out, int N) {
    int lane = threadIdx.x & 63;
    int gw = blockIdx.x * 4 + (threadIdx.x >> 6);
    int nw = gridDim.x * 4;
    int h2 = lane >> 3;
    int col = h2 * 32 + ((lane & 7) << 2);
    float4 bv = *(const float4*)(bias + col);

    for (int node = gw; node < N; node += nw) {
        int s0 = off[node], s1 = off[node + 1];

        float dsum = 0.f;
        float acc0 = 0.f, acc1 = 0.f, acc2 = 0.f, acc3 = 0.f;
        int j = s0;
        for (; j + 6 <= s1; j += 6) {
            int sA = epair[j].x, sB = epair[j + 1].x, sC = epair[j + 2].x;
            int sD = epair[j + 3].x, sE = epair[j + 4].x, sF = epair[j + 5].x;
            float aA = bf2f(pB[(size_t)j * 8 + h2]);
            float aB = bf2f(pB[(size_t)(j + 1) * 8 + h2]);
            float aC = bf2f(pB[(size_t)(j + 2) * 8 + h2]);
            float aD_ = bf2f(pB[(size_t)(j + 3) * 8 + h2]);
            float aE = bf2f(pB[(size_t)(j + 4) * 8 + h2]);
            float aF = bf2f(pB[(size_t)(j + 5) * 8 + h2]);
            us4 hA = __builtin_nontemporal_load((const us4*)(hb + (size_t)sA * 256 + col));
            us4 hB = __builtin_nontemporal_load((const us4*)(hb + (size_t)sB * 256 + col));
            us4 hC = __builtin_nontemporal_load((const us4*)(hb + (size_t)sC * 256 + col));
            us4 hD = __builtin_nontemporal_load((const us4*)(hb + (size_t)sD * 256 + col));
            us4 hE = __builtin_nontemporal_load((const us4*)(hb + (size_t)sE * 256 + col));
            us4 hF = __builtin_nontemporal_load((const us4*)(hb + (size_t)sF * 256 + col));
            dsum += aA + aB + aC + aD_ + aE + aF;
            acc0 = fmaf(aA, bf2f(hA[0]), acc0);
            acc1 = fmaf(aA, bf2f(hA[1]), acc1);
            acc2 = fmaf(aA, bf2f(hA[2]), acc2);
            acc3 = fmaf(aA, bf2f(hA[3]), acc3);
            acc0 = fmaf(aB, bf2f(hB[0]), acc0);
            acc1 = fmaf(aB, bf2f(hB[1]), acc1);
            acc2 = fmaf(aB, bf2f(hB[2]), acc2);
            acc3 = fmaf(aB, bf2f(hB[3]), acc3);
            acc0 = fmaf(aC, bf2f(hC[0]), acc0);
            acc1 = fmaf(aC, bf2f(hC[1]), acc1);
            acc2 = fmaf(aC, bf2f(hC[2]), acc2);
            acc3 = fmaf(aC, bf2f(hC[3]), acc3);
            acc0 = fmaf(aD_, bf2f(hD[0]), acc0);
            acc1 = fmaf(aD_, bf2f(hD[1]), acc1);
            acc2 = fmaf(aD_, bf2f(hD[2]), acc2);
            acc3 = fmaf(aD_, bf2f(hD[3]), acc3);
            acc0 = fmaf(aE, bf2f(hE[0]), acc0);
            acc1 = fmaf(aE, bf2f(hE[1]), acc1);
            acc2 = fmaf(aE, bf2f(hE[2]), acc2);
            acc3 = fmaf(aE, bf2f(hE[3]), acc3);
            acc0 = fmaf(aF, bf2f(hF[0]), acc0);
            acc1 = fmaf(aF, bf2f(hF[1]), acc1);
            acc2 = fmaf(aF, bf2f(hF[2]), acc2);
            acc3 = fmaf(aF, bf2f(hF[3]), acc3);
        }
        for (; j < s1; ++j) {
            int s = epair[j].x;
            float a = bf2f(pB[(size_t)j * 8 + h2]);
            us4 hv = __builtin_nontemporal_load((const us4*)(hb + (size_t)s * 256 + col));
            dsum += a;
            acc0 = fmaf(a, bf2f(hv[0]), acc0);
            acc1 = fmaf(a, bf2f(hv[1]), acc1);
            acc2 = fmaf(a, bf2f(hv[2]), acc2);
            acc3 = fmaf(a, bf2f(hv[3]), acc3);
        }
        float invh = 1.f / (dsum + 1e-16f);
        float o0 = acc0 * invh + bv.x, o1 = acc1 * invh + bv.y;
        float o2 = acc2 * invh + bv.z, o3 = acc3 * invh + bv.w;
        o0 = (o0 > 0.f) ? o0 : expm1f(o0);
        o1 = (o1 > 0.f) ? o1 : expm1f(o1);
        o2 = (o2 > 0.f) ? o2 : expm1f(o2);
        o3 = (o3 > 0.f) ? o3 : expm1f(o3);
        ushort4 q;
        q.x = f2bf(o0); q.y = f2bf(o1); q.z = f2bf(o2); q.w = f2bf(o3);
        *(ushort4*)(out + (size_t)node * 256 + col) = q;
    }
}

// ---------------- aggregate (layer 2): fused mean-readout, 4-deep (control) ----------------

__global__ __launch_bounds__(256) void aggregate_readout_kernel(
        const ushort_t* __restrict__ hb,
        const ushort_t* __restrict__ pB,
        const int* __restrict__ off,
        const int2* __restrict__ epair,
        const float* __restrict__ bias,
        float* __restrict__ bpart, int N) {
    __shared__ float gred[4 * 256];
    int lane = threadIdx.x & 63;
    int wave = threadIdx.x >> 6;
    int gw = blockIdx.x * 4 + wave;
    int nw = gridDim.x * 4;
    int h2 = lane >> 3;
    int col = h2 * 32 + ((lane & 7) << 2);
    float4 bv = *(const float4*)(bias + col);
    float g0 = 0.f, g1 = 0.f, g2 = 0.f, g3 = 0.f;

    for (int node = gw; node < N; node += nw) {
        int s0 = off[node], s1 = off[node + 1];

        float dsum = 0.f;
        float acc0 = 0.f, acc1 = 0.f, acc2 = 0.f, acc3 = 0.f;
        int j = s0;
        for (; j + 4 <= s1; j += 4) {
            int sA = epair[j].x, sB = epair[j + 1].x;
            int sC = epair[j + 2].x, sD = epair[j + 3].x;
            float aA = bf2f(pB[(size_t)j * 8 + h2]);
            float aB = bf2f(pB[(size_t)(j + 1) * 8 + h2]);
            float aC = bf2f(pB[(size_t)(j + 2) * 8 + h2]);
            float aD_ = bf2f(pB[(size_t)(j + 3) * 8 + h2]);
            us4 hA = __builtin_nontemporal_load((const us4*)(hb + (size_t)sA * 256 + col));
            us4 hB = __builtin_nontemporal_load((const us4*)(hb + (size_t)sB * 256 + col));
            us4 hC = __builtin_nontemporal_load((const us4*)(hb + (size_t)sC * 256 + col));
            us4 hD = __builtin_nontemporal_load((const us4*)(hb + (size_t)sD * 256 + col));
            dsum += aA + aB + aC + aD_;
            acc0 = fmaf(aA, bf2f(hA[0]), acc0);
            acc1 = fmaf(aA, bf2f(hA[1]), acc1);
            acc2 = fmaf(aA, bf2f(hA[2]), acc2);
            acc3 = fmaf(aA, bf2f(hA[3]), acc3);
            acc0 = fmaf(aB, bf2f(hB[0]), acc0);
            acc1 = fmaf(aB, bf2f(hB[1]), acc1);
            acc2 = fmaf(aB, bf2f(hB[2]), acc2);
            acc3 = fmaf(aB, bf2f(hB[3]), acc3);
            acc0 = fmaf(aC, bf2f(hC[0]), acc0);
            acc1 = fmaf(aC, bf2f(hC[1]), acc1);
            acc2 = fmaf(aC, bf2f(hC[2]), acc2);
            acc3 = fmaf(aC, bf2f(hC[3]), acc3);
            acc0 = fmaf(aD_, bf2f(hD[0]), acc0);
            acc1 = fmaf(aD_, bf2f(hD[1]), acc1);
            acc2 = fmaf(aD_, bf2f(hD[2]), acc2);
            acc3 = fmaf(aD_, bf2f(hD[3]), acc3);
        }
        for (; j < s1; ++j) {
            int s = epair[j].x;
            float a = bf2f(pB[(size_t)j * 8 + h2]);
            us4 hv = __builtin_nontemporal_load((const us4*)(hb + (size_t)s * 256 + col));
            dsum += a;
            acc0 = fmaf(a, bf2f(hv[0]), acc0);
            acc1 = fmaf(a, bf2f(hv[1]), acc1);
            acc2 = fmaf(a, bf2f(hv[2]), acc2);
            acc3 = fmaf(a, bf2f(hv[3]), acc3);
        }
        float invh = 1.f / (dsum + 1e-16f);
        float o0 = acc0 * invh + bv.x, o1 = acc1 * invh + bv.y;
        float o2 = acc2 * invh + bv.z, o3 = acc3 * invh + bv.w;
        o0 = (o0 > 0.f) ? o0 : expm1f(o0);
        o1 = (o1 > 0.f) ? o1 : expm1f(o1);
        o2 = (o2 > 0.f) ? o2 : expm1f(o2);
        o3 = (o3 > 0.f) ? o3 : expm1f(o3);
        g0 += bf2f(f2bf(o0));
        g1 += bf2f(f2bf(o1));
        g2 += bf2f(f2bf(o2));
        g3 += bf2f(f2bf(o3));
    }
    gred[wave * 256 + col + 0] = g0;
    gred[wave * 256 + col + 1] = g1;
    gred[wave * 256 + col + 2] = g2;
    gred[wave * 256 + col + 3] = g3;
    __syncthreads();
    int t = threadIdx.x;   // channel
    float sum = gred[t] + gred[256 + t] + gred[512 + t] + gred[768 + t];
    bpart[(size_t)blockIdx.x * 256 + t] = sum;
}

// ---------------- tree reduce: bpart[2048][256] -> bpart2[64][256] ----------------

__global__ __launch_bounds__(256) void reduce_kernel(const float* __restrict__ bpart,
                                                     float* __restrict__ bpart2) {
    int t = threadIdx.x;
    int b = blockIdx.x;           // 0..63
    float s = 0.f;
    const float* row = bpart + (size_t)b * 32 * 256;
#pragma unroll 8
    for (int r = 0; r < 32; r++)
        s += row[r * 256 + t];
    bpart2[(size_t)b * 256 + t] = s;
}

// ---------------- final: sum bpart2 rows, mean, dot with lin weights ----------------

__global__ __launch_bounds__(256) void final_kernel(const float* __restrict__ bpart2,
                                                    const float* __restrict__ lw,
                                                    const float* __restrict__ lb,
                                                    const float* __restrict__ u,
                                                    const float* __restrict__ w,
                                                    float invN, float* __restrict__ out) {
    __shared__ float s[256];
    int t = threadIdx.x;
    float v = 0.f;
#pragma unroll 8
    for (int r = 0; r < 64; r++)
        v += bpart2[(size_t)r * 256 + t];
    s[t] = v * invN * lw[t];
    __syncthreads();
    for (int o = 128; o > 0; o >>= 1) {
        if (t < o) s[t] += s[t + o];
        __syncthreads();
    }
    if (t == 0) out[0] = s[0] + u[0] * lw[256] + w[0] * lw[257] + lb[0];
}

// ---------------- launcher ----------------

extern "C" void kernel_launch(void* const* d_in, const int* in_sizes, int n_in,
                              void* d_out, int out_size, void* d_ws, size_t ws_size,
                              hipStream_t stream) {
    const float* x   = (const float*)d_in[0];
    const int*   ei  = (const int*)d_in[1];
    const float* u   = (const float*)d_in[2];
    const float* w   = (const float*)d_in[3];
    const float* W1  = (const float*)d_in[4];
    const float* as1 = (const float*)d_in[5];
    const float* ad1 = (const float*)d_in[6];
    const float* b1  = (const float*)d_in[7];
    const float* W2  = (const float*)d_in[8];
    const float* as2 = (const float*)d_in[9];
    const float* ad2 = (const float*)d_in[10];
    const float* b2  = (const float*)d_in[11];
    const float* lw  = (const float*)d_in[12];
    const float* lb  = (const float*)d_in[13];
    float* out = (float*)d_out;

    const int N = in_sizes[0] / 128;
    const int E = in_sizes[1] / 2;

    char* p = (char*)d_ws;
    auto alloc = [&](size_t bytes) -> char* {
        char* r = p;
        p += (bytes + 255) & ~(size_t)255;
        return r;
    };
    ushort_t* xb   = (ushort_t*)alloc((size_t)N * 128 * 2);
    ushort_t* hb   = (ushort_t*)alloc((size_t)N * 256 * 2);
    ushort_t* outb = (ushort_t*)alloc((size_t)N * 256 * 2);
    ushort_t* w1t  = (ushort_t*)alloc((size_t)256 * 128 * 2);
    ushort_t* w2t  = (ushort_t*)alloc((size_t)256 * 256 * 2);
    ushort_t* pB   = (ushort_t*)alloc((size_t)E * 8 * 2);
    float* aS    = (float*)alloc((size_t)N * 8 * 4);
    float* aD    = (float*)alloc((size_t)N * 8 * 4);
    float* bpart = (float*)alloc((size_t)AGG_BLOCKS * 256 * 4);
    float* bpart2= (float*)alloc((size_t)64 * 256 * 4);
    int* off     = (int*)alloc((size_t)(N + 1) * 4);
    int* deg     = (int*)alloc((size_t)N * 4);
    int* bsums   = (int*)alloc(256 * 4);
    int2* epair  = (int2*)alloc((size_t)E * 8);
    int* rank    = (int*)alloc((size_t)E * 4);

    (void)hipMemsetAsync(deg, 0, (size_t)N * 4, stream);

    const int NB = (N + 255) / 256;
    const int EB = (E + 255) / 256;
    const int XB = (N * 128 / 4 + 255) / 256;

    prep_kernel<<<XB + 384, 256, 0, stream>>>(x, xb, N * 128 / 4, XB, W1, w1t, W2, w2t);
    hist_kernel<<<EB, 256, 0, stream>>>(ei + E, E, deg, rank);
    scan_block<<<NB, 256, 0, stream>>>(deg, N, off, bsums);
    scan_sums<<<1, 256, 0, stream>>>(bsums, NB);
    scan_add<<<NB, 256, 0, stream>>>(off, bsums, N, E);
    scatter_inv_kernel<<<EB, 256, 0, stream>>>(ei, E, off, rank, epair);

    dim3 ggrid((N + 127) / 128, 2);
    // layer 1 (alpha fused into gemm epilogue)
    gemm_mfma<<<ggrid, 256, 0, stream>>>(xb, w1t, hb, N, 128, as1, ad1, aS, aD);
    pexp_stream_kernel<<<EB, 256, 0, stream>>>(epair, aS, aD, pB, E);
    aggregate_kernel<<<AGG_BLOCKS, 256, 0, stream>>>(hb, pB, off, epair, b1, outb, N);
    // layer 2 (readout fused into aggregate; atomic-free combine)
    gemm_mfma<<<ggrid, 256, 0, stream>>>(outb, w2t, hb, N, 256, as2, ad2, aS, aD);
    pexp_stream_kernel<<<EB, 256, 0, stream>>>(epair, aS, aD, pB, E);
    aggregate_readout_kernel<<<AGG_BLOCKS, 256, 0, stream>>>(hb, pB, off, epair, b2, bpart, N);
    reduce_kernel<<<64, 256, 0, stream>>>(bpart, bpart2);
    final_kernel<<<1, 256, 0, stream>>>(bpart2, lw, lb, u, w, 1.0f / (float)N, out);
}

// Round 18
// 278.026 us; speedup vs baseline: 1.3132x; 1.3132x over previous
//
#include <hip/hip_runtime.h>
#include <math.h>

typedef unsigned short ushort_t;
typedef __attribute__((ext_vector_type(8))) short short8;
typedef __attribute__((ext_vector_type(4))) float f32x4;

__device__ __forceinline__ unsigned short f2bf(float f) {
    unsigned u = __float_as_uint(f);
    unsigned r = (u + 0x7fffu + ((u >> 16) & 1u)) >> 16;   // RNE
    return (unsigned short)r;
}
__device__ __forceinline__ float bf2f(unsigned short b) {
    return __uint_as_float(((unsigned)b) << 16);
}

__device__ __forceinline__ void gld_lds16(const ushort_t* g, ushort_t* l) {
    __builtin_amdgcn_global_load_lds(
        (const __attribute__((address_space(1))) unsigned int*)g,
        (__attribute__((address_space(3))) unsigned int*)l,
        16, 0, 0);
}

#define AGG_BLOCKS 2048

// ---------------- fused prep: x->bf16, W1->W1t, W2->W2t ----------------

__global__ __launch_bounds__(256) void prep_kernel(const float* __restrict__ x,
                                                   ushort_t* __restrict__ xb, int n4, int XB,
                                                   const float* __restrict__ W1,
                                                   ushort_t* __restrict__ w1t,
                                                   const float* __restrict__ W2,
                                                   ushort_t* __restrict__ w2t) {
    int b = blockIdx.x;
    if (b < XB) {
        int i = b * 256 + threadIdx.x;
        if (i < n4) {
            float4 v = *(const float4*)(x + (size_t)i * 4);
            ushort4 q;
            q.x = f2bf(v.x); q.y = f2bf(v.y); q.z = f2bf(v.z); q.w = f2bf(v.w);
            *(ushort4*)(xb + (size_t)i * 4) = q;
        }
    } else if (b < XB + 128) {
        int idx = (b - XB) * 256 + threadIdx.x;   // over 128*256
        int k = idx >> 8, n = idx & 255;
        w1t[(size_t)n * 128 + k] = f2bf(W1[idx]);
    } else {
        int idx = (b - XB - 128) * 256 + threadIdx.x; // over 256*256
        int k = idx >> 8, n = idx & 255;
        w2t[(size_t)n * 256 + k] = f2bf(W2[idx]);
    }
}

// ---------------- CSR build: hist assigns within-segment rank ----------------

__global__ __launch_bounds__(256) void hist_kernel(const int* __restrict__ dst, int E,
                                                   int* __restrict__ deg,
                                                   int* __restrict__ rank) {
    int e = blockIdx.x * 256 + threadIdx.x;
    if (e < E) rank[e] = atomicAdd(&deg[dst[e]], 1);
}

__global__ __launch_bounds__(256) void scan_block(const int* __restrict__ in, int n,
                                                  int* __restrict__ out, int* __restrict__ bsums) {
    __shared__ int s[256];
    int t = threadIdx.x;
    int i = blockIdx.x * 256 + t;
    int v = (i < n) ? in[i] : 0;
    s[t] = v;
    __syncthreads();
#pragma unroll
    for (int o = 1; o < 256; o <<= 1) {
        int y = (t >= o) ? s[t - o] : 0;
        __syncthreads();
        s[t] += y;
        __syncthreads();
    }
    if (i < n) out[i] = s[t] - v;
    if (t == 255) bsums[blockIdx.x] = s[255];
}

__global__ __launch_bounds__(256) void scan_sums(int* __restrict__ bsums, int nb) {
    __shared__ int s[256];
    int t = threadIdx.x;
    int v = (t < nb) ? bsums[t] : 0;
    s[t] = v;
    __syncthreads();
#pragma unroll
    for (int o = 1; o < 256; o <<= 1) {
        int y = (t >= o) ? s[t - o] : 0;
        __syncthreads();
        s[t] += y;
        __syncthreads();
    }
    if (t < nb) bsums[t] = s[t] - v;
}

__global__ __launch_bounds__(256) void scan_add(int* __restrict__ off,
                                                const int* __restrict__ bsums, int N, int E) {
    int i = blockIdx.x * 256 + threadIdx.x;
    if (i < N) off[i] += bsums[blockIdx.x];
    if (i == 0) off[N] = E;
}

// ---------------- CSR placement: (src,dst) packed, ONE 8B random store/edge ----------------

__global__ __launch_bounds__(256) void scatter_inv_kernel(const int* __restrict__ ei, int E,
                                                          const int* __restrict__ off,
                                                          const int* __restrict__ rank,
                                                          int2* __restrict__ epair) {
    int e = blockIdx.x * 256 + threadIdx.x;
    if (e < E) {
        int s = ei[e], d = ei[E + e];
        int pos = off[d] + rank[e];
        epair[pos] = make_int2(s, d);
    }
}

// ---------------- bf16 MFMA GEMM + fused alpha epilogue ----------------

__device__ __forceinline__ int swz4(int r) { return (r ^ (r >> 2)) & 3; }

__global__ __launch_bounds__(256) void gemm_mfma(const ushort_t* __restrict__ A,
                                                 const ushort_t* __restrict__ Bt,
                                                 ushort_t* __restrict__ C, int M, int K,
                                                 const float* __restrict__ a_src,
                                                 const float* __restrict__ a_dst,
                                                 float* __restrict__ aS,
                                                 float* __restrict__ aD) {
    __shared__ ushort_t smem[2 * 128 * 32];     // K-loop: As | Bs ; epilogue: [64][128] stage
    ushort_t* As = smem;
    ushort_t* Bs = smem + 128 * 32;
    const int tid = threadIdx.x;
    const int lane = tid & 63;
    const int wave = tid >> 6;
    const int bm = blockIdx.x * 128;
    const int bn = blockIdx.y * 128;
    const int head_base = blockIdx.y * 4;
    const int wr = (wave >> 1) * 64;
    const int wc = (wave & 1) * 64;

    const int G0 = wave * 2, G1 = wave * 2 + 1;
    const int rl = lane >> 2;
    const int sl = lane & 3;
    const int RA0 = G0 * 16 + rl, RA1 = G1 * 16 + rl;
    const int sA0 = sl ^ swz4(RA0), sA1 = sl ^ swz4(RA1);
    const int gA0 = min(bm + RA0, M - 1);
    const int gA1 = min(bm + RA1, M - 1);
    const ushort_t* srcA0 = A + (size_t)gA0 * K + sA0 * 8;
    const ushort_t* srcA1 = A + (size_t)gA1 * K + sA1 * 8;
    const ushort_t* srcB0 = Bt + (size_t)(bn + RA0) * K + sA0 * 8;
    const ushort_t* srcB1 = Bt + (size_t)(bn + RA1) * K + sA1 * 8;
    ushort_t* dA0 = &As[G0 * 512];
    ushort_t* dA1 = &As[G1 * 512];
    ushort_t* dB0 = &Bs[G0 * 512];
    ushort_t* dB1 = &Bs[G1 * 512];

    int offA[4], offB[4];
    const int c = lane >> 4;
    const int fr = lane & 15;
#pragma unroll
    for (int mi = 0; mi < 4; mi++) {
        int r = wr + mi * 16 + fr;
        offA[mi] = r * 32 + (c ^ swz4(r)) * 8;
    }
#pragma unroll
    for (int ni = 0; ni < 4; ni++) {
        int r = wc + ni * 16 + fr;
        offB[ni] = r * 32 + (c ^ swz4(r)) * 8;
    }

    f32x4 acc[4][4];
#pragma unroll
    for (int i = 0; i < 4; i++)
#pragma unroll
        for (int j = 0; j < 4; j++)
            acc[i][j] = (f32x4){0.f, 0.f, 0.f, 0.f};

    const int nk = K >> 5;
    gld_lds16(srcA0, dA0);
    gld_lds16(srcA1, dA1);
    gld_lds16(srcB0, dB0);
    gld_lds16(srcB1, dB1);

    for (int kk = 0; kk < nk; kk++) {
        __syncthreads();
        short8 af[4], bf[4];
#pragma unroll
        for (int mi = 0; mi < 4; mi++) af[mi] = *(const short8*)&As[offA[mi]];
#pragma unroll
        for (int ni = 0; ni < 4; ni++) bf[ni] = *(const short8*)&Bs[offB[ni]];
#pragma unroll
        for (int mi = 0; mi < 4; mi++)
#pragma unroll
            for (int ni = 0; ni < 4; ni++)
                acc[mi][ni] = __builtin_amdgcn_mfma_f32_16x16x32_bf16(af[mi], bf[ni],
                                                                      acc[mi][ni], 0, 0, 0);
        __syncthreads();
        if (kk + 1 < nk) {
            int k0 = (kk + 1) * 32;
            gld_lds16(srcA0 + k0, dA0);
            gld_lds16(srcA1 + k0, dA1);
            gld_lds16(srcB0 + k0, dB0);
            gld_lds16(srcB1 + k0, dB1);
        }
    }

    // epilogue: stage 64 rows in LDS; b128 global stores; fused alpha dots.
    const int rq = (lane >> 4) * 4;
#pragma unroll
    for (int half = 0; half < 2; half++) {
        __syncthreads();
        if ((wave >> 1) == half) {
#pragma unroll
            for (int mi = 0; mi < 4; mi++)
#pragma unroll
                for (int j = 0; j < 4; j++) {
                    int rowl = mi * 16 + rq + j;
#pragma unroll
                    for (int ni = 0; ni < 4; ni++)
                        smem[rowl * 128 + wc + ni * 16 + fr] = f2bf(acc[mi][ni][j]);
                }
        }
        __syncthreads();
#pragma unroll
        for (int q2 = 0; q2 < 4; q2++) {
            int cidx = q2 * 256 + tid;       // 16B-chunk index 0..1023 in [64][128]
            int r = cidx >> 4;               // row 0..63
            int ck = cidx & 15;              // chunk in row (8 cols each)
            int grow = bm + half * 64 + r;
            uint4 v = *(const uint4*)&smem[cidx * 8];
            if (grow < M)
                *(uint4*)(C + (size_t)grow * 256 + bn + ck * 8) = v;
            int hd = ck >> 2, qq = ck & 3;
            const float* apS = a_src + (head_base + hd) * 32 + qq * 8;
            const float* apD = a_dst + (head_base + hd) * 32 + qq * 8;
            float4 s0v = *(const float4*)apS, s1v = *(const float4*)(apS + 4);
            float4 d0v = *(const float4*)apD, d1v = *(const float4*)(apD + 4);
            unsigned uu[4] = {v.x, v.y, v.z, v.w};
            float as_[8] = {s0v.x, s0v.y, s0v.z, s0v.w, s1v.x, s1v.y, s1v.z, s1v.w};
            float ad_[8] = {d0v.x, d0v.y, d0v.z, d0v.w, d1v.x, d1v.y, d1v.z, d1v.w};
            float sp = 0.f, dp = 0.f;
#pragma unroll
            for (int pp = 0; pp < 4; pp++) {
                float h0 = bf2f((unsigned short)(uu[pp] & 0xffffu));
                float h1 = bf2f((unsigned short)(uu[pp] >> 16));
                sp = fmaf(h0, as_[2 * pp], sp);
                sp = fmaf(h1, as_[2 * pp + 1], sp);
                dp = fmaf(h0, ad_[2 * pp], dp);
                dp = fmaf(h1, ad_[2 * pp + 1], dp);
            }
            sp += __shfl_xor(sp, 1);
            sp += __shfl_xor(sp, 2);
            dp += __shfl_xor(dp, 1);
            dp += __shfl_xor(dp, 2);
            if (qq == 0 && grow < M) {
                aS[(size_t)grow * 8 + head_base + hd] = sp;
                aD[(size_t)grow * 8 + head_base + hd] = dp;
            }
        }
    }
}

// ---------------- position-major p = exp(leaky(aS+aD)); also materializes esrc ----------------

__global__ __launch_bounds__(256) void pexp_stream_kernel(const int2* __restrict__ epair,
                                                          const float* __restrict__ aS,
                                                          const float* __restrict__ aD,
                                                          ushort_t* __restrict__ pB,
                                                          int* __restrict__ esrc, int E) {
    int j = blockIdx.x * 256 + threadIdx.x;
    if (j >= E) return;
    int2 sd = epair[j];
    esrc[j] = sd.x;                      // coalesced; idempotent across layers
    const float4* sp = (const float4*)(aS + (size_t)sd.x * 8);
    const float4* dp = (const float4*)(aD + (size_t)sd.y * 8);
    float4 sv0 = sp[0], sv1 = sp[1], dv0 = dp[0], dv1 = dp[1];
    float ev[8] = {sv0.x + dv0.x, sv0.y + dv0.y, sv0.z + dv0.z, sv0.w + dv0.w,
                   sv1.x + dv1.x, sv1.y + dv1.y, sv1.z + dv1.z, sv1.w + dv1.w};
    ushort_t q[8];
#pragma unroll
    for (int h = 0; h < 8; h++) {
        float x = ev[h];
        x = (x > 0.f) ? x : 0.2f * x;
        q[h] = f2bf(__expf(x));
    }
    *(uint4*)(pB + (size_t)j * 8) = *(uint4*)q;
}

// ---------------- aggregate (layer 1): r15-proven form -> out ----------------

__global__ __launch_bounds__(256) void aggregate_kernel(const ushort_t* __restrict__ hb,
                                                        const ushort_t* __restrict__ pB,
                                                        const int* __restrict__ off,
                                                        const int* __restrict__ esrc,
                                                        const float* __restrict__ bias,
                                                        ushort_t* __restrict__ out, int N) {
    int lane = threadIdx.x & 63;
    int gw = blockIdx.x * 4 + (threadIdx.x >> 6);
    int nw = gridDim.x * 4;
    int h2 = lane >> 3;
    int col = h2 * 32 + ((lane & 7) << 2);
    float4 bv = *(const float4*)(bias + col);

    for (int node = gw; node < N; node += nw) {
        int s0 = off[node], s1 = off[node + 1];

        float dsum = 0.f;
        float acc0 = 0.f, acc1 = 0.f, acc2 = 0.f, acc3 = 0.f;
        int j = s0;
        for (; j + 4 <= s1; j += 4) {
            int sA = esrc[j], sB = esrc[j + 1], sC = esrc[j + 2], sD = esrc[j + 3];
            float aA = bf2f(pB[(size_t)j * 8 + h2]);
            float aB = bf2f(pB[(size_t)(j + 1) * 8 + h2]);
            float aC = bf2f(pB[(size_t)(j + 2) * 8 + h2]);
            float aD_ = bf2f(pB[(size_t)(j + 3) * 8 + h2]);
            ushort4 hA = *(const ushort4*)(hb + (size_t)sA * 256 + col);
            ushort4 hB = *(const ushort4*)(hb + (size_t)sB * 256 + col);
            ushort4 hC = *(const ushort4*)(hb + (size_t)sC * 256 + col);
            ushort4 hD = *(const ushort4*)(hb + (size_t)sD * 256 + col);
            dsum += aA + aB + aC + aD_;
            acc0 = fmaf(aA, bf2f(hA.x), acc0);
            acc1 = fmaf(aA, bf2f(hA.y), acc1);
            acc2 = fmaf(aA, bf2f(hA.z), acc2);
            acc3 = fmaf(aA, bf2f(hA.w), acc3);
            acc0 = fmaf(aB, bf2f(hB.x), acc0);
            acc1 = fmaf(aB, bf2f(hB.y), acc1);
            acc2 = fmaf(aB, bf2f(hB.z), acc2);
            acc3 = fmaf(aB, bf2f(hB.w), acc3);
            acc0 = fmaf(aC, bf2f(hC.x), acc0);
            acc1 = fmaf(aC, bf2f(hC.y), acc1);
            acc2 = fmaf(aC, bf2f(hC.z), acc2);
            acc3 = fmaf(aC, bf2f(hC.w), acc3);
            acc0 = fmaf(aD_, bf2f(hD.x), acc0);
            acc1 = fmaf(aD_, bf2f(hD.y), acc1);
            acc2 = fmaf(aD_, bf2f(hD.z), acc2);
            acc3 = fmaf(aD_, bf2f(hD.w), acc3);
        }
        for (; j < s1; ++j) {
            int s = esrc[j];
            float a = bf2f(pB[(size_t)j * 8 + h2]);
            ushort4 hv = *(const ushort4*)(hb + (size_t)s * 256 + col);
            dsum += a;
            acc0 = fmaf(a, bf2f(hv.x), acc0);
            acc1 = fmaf(a, bf2f(hv.y), acc1);
            acc2 = fmaf(a, bf2f(hv.z), acc2);
            acc3 = fmaf(a, bf2f(hv.w), acc3);
        }
        float invh = 1.f / (dsum + 1e-16f);
        float o0 = acc0 * invh + bv.x, o1 = acc1 * invh + bv.y;
        float o2 = acc2 * invh + bv.z, o3 = acc3 * invh + bv.w;
        o0 = (o0 > 0.f) ? o0 : expm1f(o0);
        o1 = (o1 > 0.f) ? o1 : expm1f(o1);
        o2 = (o2 > 0.f) ? o2 : expm1f(o2);
        o3 = (o3 > 0.f) ? o3 : expm1f(o3);
        ushort4 q;
        q.x = f2bf(o0); q.y = f2bf(o1); q.z = f2bf(o2); q.w = f2bf(o3);
        *(ushort4*)(out + (size_t)node * 256 + col) = q;
    }
}

// ---------------- aggregate (layer 2): fused mean-readout (r15-proven) ----------------

__global__ __launch_bounds__(256) void aggregate_readout_kernel(
        const ushort_t* __restrict__ hb,
        const ushort_t* __restrict__ pB,
        const int* __restrict__ off,
        const int* __restrict__ esrc,
        const float* __restrict__ bias,
        float* __restrict__ bpart, int N) {
    __shared__ float gred[4 * 256];
    int lane = threadIdx.x & 63;
    int wave = threadIdx.x >> 6;
    int gw = blockIdx.x * 4 + wave;
    int nw = gridDim.x * 4;
    int h2 = lane >> 3;
    int col = h2 * 32 + ((lane & 7) << 2);
    float4 bv = *(const float4*)(bias + col);
    float g0 = 0.f, g1 = 0.f, g2 = 0.f, g3 = 0.f;

    for (int node = gw; node < N; node += nw) {
        int s0 = off[node], s1 = off[node + 1];

        float dsum = 0.f;
        float acc0 = 0.f, acc1 = 0.f, acc2 = 0.f, acc3 = 0.f;
        int j = s0;
        for (; j + 4 <= s1; j += 4) {
            int sA = esrc[j], sB = esrc[j + 1], sC = esrc[j + 2], sD = esrc[j + 3];
            float aA = bf2f(pB[(size_t)j * 8 + h2]);
            float aB = bf2f(pB[(size_t)(j + 1) * 8 + h2]);
            float aC = bf2f(pB[(size_t)(j + 2) * 8 + h2]);
            float aD_ = bf2f(pB[(size_t)(j + 3) * 8 + h2]);
            ushort4 hA = *(const ushort4*)(hb + (size_t)sA * 256 + col);
            ushort4 hB = *(const ushort4*)(hb + (size_t)sB * 256 + col);
            ushort4 hC = *(const ushort4*)(hb + (size_t)sC * 256 + col);
            ushort4 hD = *(const ushort4*)(hb + (size_t)sD * 256 + col);
            dsum += aA + aB + aC + aD_;
            acc0 = fmaf(aA, bf2f(hA.x), acc0);
            acc1 = fmaf(aA, bf2f(hA.y), acc1);
            acc2 = fmaf(aA, bf2f(hA.z), acc2);
            acc3 = fmaf(aA, bf2f(hA.w), acc3);
            acc0 = fmaf(aB, bf2f(hB.x), acc0);
            acc1 = fmaf(aB, bf2f(hB.y), acc1);
            acc2 = fmaf(aB, bf2f(hB.z), acc2);
            acc3 = fmaf(aB, bf2f(hB.w), acc3);
            acc0 = fmaf(aC, bf2f(hC.x), acc0);
            acc1 = fmaf(aC, bf2f(hC.y), acc1);
            acc2 = fmaf(aC, bf2f(hC.z), acc2);
            acc3 = fmaf(aC, bf2f(hC.w), acc3);
            acc0 = fmaf(aD_, bf2f(hD.x), acc0);
            acc1 = fmaf(aD_, bf2f(hD.y), acc1);
            acc2 = fmaf(aD_, bf2f(hD.z), acc2);
            acc3 = fmaf(aD_, bf2f(hD.w), acc3);
        }
        for (; j < s1; ++j) {
            int s = esrc[j];
            float a = bf2f(pB[(size_t)j * 8 + h2]);
            ushort4 hv = *(const ushort4*)(hb + (size_t)s * 256 + col);
            dsum += a;
            acc0 = fmaf(a, bf2f(hv.x), acc0);
            acc1 = fmaf(a, bf2f(hv.y), acc1);
            acc2 = fmaf(a, bf2f(hv.z), acc2);
            acc3 = fmaf(a, bf2f(hv.w), acc3);
        }
        float invh = 1.f / (dsum + 1e-16f);
        float o0 = acc0 * invh + bv.x, o1 = acc1 * invh + bv.y;
        float o2 = acc2 * invh + bv.z, o3 = acc3 * invh + bv.w;
        o0 = (o0 > 0.f) ? o0 : expm1f(o0);
        o1 = (o1 > 0.f) ? o1 : expm1f(o1);
        o2 = (o2 > 0.f) ? o2 : expm1f(o2);
        o3 = (o3 > 0.f) ? o3 : expm1f(o3);
        g0 += bf2f(f2bf(o0));
        g1 += bf2f(f2bf(o1));
        g2 += bf2f(f2bf(o2));
        g3 += bf2f(f2bf(o3));
    }
    gred[wave * 256 + col + 0] = g0;
    gred[wave * 256 + col + 1] = g1;
    gred[wave * 256 + col + 2] = g2;
    gred[wave * 256 + col + 3] = g3;
    __syncthreads();
    int t = threadIdx.x;   // channel
    float sum = gred[t] + gred[256 + t] + gred[512 + t] + gred[768 + t];
    bpart[(size_t)blockIdx.x * 256 + t] = sum;
}

// ---------------- tree reduce: bpart[2048][256] -> bpart2[64][256] ----------------

__global__ __launch_bounds__(256) void reduce_kernel(const float* __restrict__ bpart,
                                                     float* __restrict__ bpart2) {
    int t = threadIdx.x;
    int b = blockIdx.x;           // 0..63
    float s = 0.f;
    const float* row = bpart + (size_t)b * 32 * 256;
#pragma unroll 8
    for (int r = 0; r < 32; r++)
        s += row[r * 256 + t];
    bpart2[(size_t)b * 256 + t] = s;
}

// ---------------- final: sum bpart2 rows, mean, dot with lin weights ----------------

__global__ __launch_bounds__(256) void final_kernel(const float* __restrict__ bpart2,
                                                    const float* __restrict__ lw,
                                                    const float* __restrict__ lb,
                                                    const float* __restrict__ u,
                                                    const float* __restrict__ w,
                                                    float invN, float* __restrict__ out) {
    __shared__ float s[256];
    int t = threadIdx.x;
    float v = 0.f;
#pragma unroll 8
    for (int r = 0; r < 64; r++)
        v += bpart2[(size_t)r * 256 + t];
    s[t] = v * invN * lw[t];
    __syncthreads();
    for (int o = 128; o > 0; o >>= 1) {
        if (t < o) s[t] += s[t + o];
        __syncthreads();
    }
    if (t == 0) out[0] = s[0] + u[0] * lw[256] + w[0] * lw[257] + lb[0];
}

// ---------------- launcher ----------------

extern "C" void kernel_launch(void* const* d_in, const int* in_sizes, int n_in,
                              void* d_out, int out_size, void* d_ws, size_t ws_size,
                              hipStream_t stream) {
    const float* x   = (const float*)d_in[0];
    const int*   ei  = (const int*)d_in[1];
    const float* u   = (const float*)d_in[2];
    const float* w   = (const float*)d_in[3];
    const float* W1  = (const float*)d_in[4];
    const float* as1 = (const float*)d_in[5];
    const float* ad1 = (const float*)d_in[6];
    const float* b1  = (const float*)d_in[7];
    const float* W2  = (const float*)d_in[8];
    const float* as2 = (const float*)d_in[9];
    const float* ad2 = (const float*)d_in[10];
    const float* b2  = (const float*)d_in[11];
    const float* lw  = (const float*)d_in[12];
    const float* lb  = (const float*)d_in[13];
    float* out = (float*)d_out;

    const int N = in_sizes[0] / 128;
    const int E = in_sizes[1] / 2;

    char* p = (char*)d_ws;
    auto alloc = [&](size_t bytes) -> char* {
        char* r = p;
        p += (bytes + 255) & ~(size_t)255;
        return r;
    };
    ushort_t* xb   = (ushort_t*)alloc((size_t)N * 128 * 2);
    ushort_t* hb   = (ushort_t*)alloc((size_t)N * 256 * 2);
    ushort_t* outb = (ushort_t*)alloc((size_t)N * 256 * 2);
    ushort_t* w1t  = (ushort_t*)alloc((size_t)256 * 128 * 2);
    ushort_t* w2t  = (ushort_t*)alloc((size_t)256 * 256 * 2);
    ushort_t* pB   = (ushort_t*)alloc((size_t)E * 8 * 2);
    float* aS    = (float*)alloc((size_t)N * 8 * 4);
    float* aD    = (float*)alloc((size_t)N * 8 * 4);
    float* bpart = (float*)alloc((size_t)AGG_BLOCKS * 256 * 4);
    float* bpart2= (float*)alloc((size_t)64 * 256 * 4);
    int* off     = (int*)alloc((size_t)(N + 1) * 4);
    int* deg     = (int*)alloc((size_t)N * 4);
    int* bsums   = (int*)alloc(256 * 4);
    int2* epair  = (int2*)alloc((size_t)E * 8);
    int* esrc    = (int*)alloc((size_t)E * 4);
    int* rank    = (int*)alloc((size_t)E * 4);

    (void)hipMemsetAsync(deg, 0, (size_t)N * 4, stream);

    const int NB = (N + 255) / 256;
    const int EB = (E + 255) / 256;
    const int XB = (N * 128 / 4 + 255) / 256;

    prep_kernel<<<XB + 384, 256, 0, stream>>>(x, xb, N * 128 / 4, XB, W1, w1t, W2, w2t);
    hist_kernel<<<EB, 256, 0, stream>>>(ei + E, E, deg, rank);
    scan_block<<<NB, 256, 0, stream>>>(deg, N, off, bsums);
    scan_sums<<<1, 256, 0, stream>>>(bsums, NB);
    scan_add<<<NB, 256, 0, stream>>>(off, bsums, N, E);
    scatter_inv_kernel<<<EB, 256, 0, stream>>>(ei, E, off, rank, epair);

    dim3 ggrid((N + 127) / 128, 2);
    // layer 1 (alpha fused into gemm epilogue)
    gemm_mfma<<<ggrid, 256, 0, stream>>>(xb, w1t, hb, N, 128, as1, ad1, aS, aD);
    pexp_stream_kernel<<<EB, 256, 0, stream>>>(epair, aS, aD, pB, esrc, E);
    aggregate_kernel<<<AGG_BLOCKS, 256, 0, stream>>>(hb, pB, off, esrc, b1, outb, N);
    // layer 2 (readout fused into aggregate; atomic-free combine)
    gemm_mfma<<<ggrid, 256, 0, stream>>>(outb, w2t, hb, N, 256, as2, ad2, aS, aD);
    pexp_stream_kernel<<<EB, 256, 0, stream>>>(epair, aS, aD, pB, esrc, E);
    aggregate_readout_kernel<<<AGG_BLOCKS, 256, 0, stream>>>(hb, pB, off, esrc, b2, bpart, N);
    reduce_kernel<<<64, 256, 0, stream>>>(bpart, bpart2);
    final_kernel<<<1, 256, 0, stream>>>(bpart2, lw, lb, u, w, 1.0f / (float)N, out);
}